// Round 2
// baseline (182.642 us; speedup 1.0000x reference)
//
#include <hip/hip_runtime.h>
#include <math.h>

#define NB    128
#define NC    16      // replicated LDS histogram copies
#define CSTR  129     // copy stride in floats (129 % 32 == 1 -> spreads banks)

__global__ __launch_bounds__(256) void hist_kernel(const float* __restrict__ x,
                                                   const float* __restrict__ edges,
                                                   float* __restrict__ ws,
                                                   int n, int nthreads_total) {
    __shared__ float sh[NC * CSTR];
    for (int i = threadIdx.x; i < NC * CSTR; i += 256) sh[i] = 0.0f;
    __syncthreads();

    const float e0 = edges[0];
    const float res = edges[1] - e0;
    const float inv_res = 1.0f / res;
    const float C = 4.5f;                 // ndtr(-4.5) = 3.4e-6 -> bias ~5e-5 on output
    const float is2 = 0.70710678118654752440f;
    const int cbase = (threadIdx.x & (NC - 1)) * CSTR;

    for (int i = blockIdx.x * 256 + threadIdx.x; i < n; i += nthreads_total) {
        float t = (x[i * 6] - e0) * inv_res;   // z_j = j - t, edges exactly 1 bandwidth apart
        int j0 = (int)ceilf(t - C - 1.0f);
        int j1 = (int)floorf(t + C);
        j0 = max(j0, 0);
        j1 = min(j1, NB - 1);
        if (j0 > j1) continue;
        float cp = 0.5f * (1.0f + erff(((float)j0 - t) * is2));
        for (int j = j0; j <= j1; ++j) {
            float cn = 0.5f * (1.0f + erff(((float)(j + 1) - t) * is2));
            atomicAdd(&sh[cbase + j], cn - cp);
            cp = cn;
        }
    }
    __syncthreads();

    // fold the 16 copies, write this block's partial row (no global atomics)
    for (int j = threadIdx.x; j < NB; j += 256) {
        float v = 0.0f;
        #pragma unroll
        for (int c = 0; c < NC; ++c) v += sh[c * CSTR + j];
        ws[(size_t)blockIdx.x * NB + j] = v;
    }
}

__global__ __launch_bounds__(1024) void finalize_kernel(const float* __restrict__ ws,
                                                        const float* __restrict__ edges,
                                                        float* __restrict__ out, int B) {
    __shared__ float part[8 * NB];
    __shared__ float binsum[NB];
    __shared__ float red[NB];
    const int tid = threadIdx.x;
    const int j = tid & (NB - 1);
    const int s = tid >> 7;                 // 8 slices over rows

    float acc = 0.0f;
    for (int r = s; r < B; r += 8) acc += ws[(size_t)r * NB + j];  // coalesced
    part[s * NB + j] = acc;
    __syncthreads();

    if (tid < NB) {
        float tj = 0.0f;
        #pragma unroll
        for (int s2 = 0; s2 < 8; ++s2) tj += part[s2 * NB + tid];
        binsum[tid] = tj;
        red[tid] = tj;
    }
    __syncthreads();
    for (int off = NB / 2; off >= 1; off >>= 1) {
        if (tid < off) red[tid] += red[tid + off];
        __syncthreads();
    }
    if (tid < NB) {
        float res = edges[1] - edges[0];
        out[tid] = binsum[tid] / (red[0] * res);
    }
}

extern "C" void kernel_launch(void* const* d_in, const int* in_sizes, int n_in,
                              void* d_out, int out_size, void* d_ws, size_t ws_size,
                              hipStream_t stream) {
    const float* x     = (const float*)d_in[0];
    const float* edges = (const float*)d_in[1];
    float* out = (float*)d_out;
    float* ws  = (float*)d_ws;
    int n = in_sizes[0] / 6;

    int B = 2048;                                   // partial rows: B * 128 * 4 B = 1 MB
    size_t need = (size_t)B * NB * sizeof(float);
    if (ws_size < need) {
        B = (int)(ws_size / (NB * sizeof(float)));  // degrade gracefully if ws is small
        if (B < 1) B = 1;
    }

    hist_kernel<<<B, 256, 0, stream>>>(x, edges, ws, n, B * 256);
    finalize_kernel<<<1, 1024, 0, stream>>>(ws, edges, out, B);
}